// Round 15
// baseline (234.167 us; speedup 1.0000x reference)
//
#include <hip/hip_runtime.h>
#include <math.h>

typedef __attribute__((ext_vector_type(8))) short bf16x8;
typedef __attribute__((ext_vector_type(4))) float f32x4;

static __device__ __forceinline__ float fast_elu(float x) {
    return x > 0.0f ? x : __expf(x) - 1.0f;
}

static __device__ __forceinline__ unsigned short f2bf(float f) {
    unsigned int u = __float_as_uint(f);
    unsigned int r = (u + 0x7FFFu + ((u >> 16) & 1u)) >> 16;
    return (unsigned short)r;
}

static __device__ __forceinline__ bf16x8 cvt8(const float* __restrict__ s) {
    float4 a = *reinterpret_cast<const float4*>(s);
    float4 b = *reinterpret_cast<const float4*>(s + 4);
    bf16x8 r;
    r[0] = (short)f2bf(a.x); r[1] = (short)f2bf(a.y);
    r[2] = (short)f2bf(a.z); r[3] = (short)f2bf(a.w);
    r[4] = (short)f2bf(b.x); r[5] = (short)f2bf(b.y);
    r[6] = (short)f2bf(b.z); r[7] = (short)f2bf(b.w);
    return r;
}

// conv segments in 8-element units (xb/fcinWb now fused into fc_in GEMM)
#define T0 16384    // fc1Wb   [128,1024]
#define T1 16896    // Wb      [64,64]
#define T2 82432    // out1WbT [4096,128] row-permuted
#define T3 99328    // Gb      [2112,64] = tgw cols 0:64
#define CONV_BLOCKS 388   // T3/256

// ---------------------------------------------------------------------------
// Phase device functions
// ---------------------------------------------------------------------------
static __device__ __forceinline__ void conv_phase(
    int bx,
    const float* __restrict__ fc1W, const float* __restrict__ ntW,
    const float* __restrict__ out1W, const float* __restrict__ tgw,
    unsigned short* __restrict__ fc1Wb, unsigned short* __restrict__ Wb,
    unsigned short* __restrict__ out1WbT, unsigned short* __restrict__ Gb)
{
    int u = bx * 256 + threadIdx.x;
    if (u < T0) {
        int i8 = u * 8;
        *reinterpret_cast<bf16x8*>(&fc1Wb[i8]) = cvt8(&fc1W[i8]);
    } else if (u < T1) {
        int i8 = (u - T0) * 8;
        *reinterpret_cast<bf16x8*>(&Wb[i8]) = cvt8(&ntW[i8]);
    } else if (u < T2) {
        int i = u - T1;
        int n = i >> 4, kc = i & 15;
        int d = n >> 6, p = n & 63;
        *reinterpret_cast<bf16x8*>(&out1WbT[(size_t)n * 128 + kc * 8]) =
            cvt8(&out1W[(size_t)((p << 6) | d) * 128 + kc * 8]);
    } else if (u < T3) {
        int i = u - T2;
        int e = i >> 3, c = i & 7;
        *reinterpret_cast<bf16x8*>(&Gb[(size_t)e * 64 + c * 8]) =
            cvt8(&tgw[(size_t)e * 2112 + c * 8]);
    }
}

static __device__ __forceinline__ void coef_phase(
    int bx, float* __restrict__ smemf,
    const float* __restrict__ coef_m, const float* __restrict__ cW,
    const float* __restrict__ cB, const float* __restrict__ attW,
    float* __restrict__ cfs)
{
    float* cf_s = smemf;            // [4][256]
    float* part = smemf + 1024;     // [4][64]
    const int t = threadIdx.x;
    const int wv = t >> 6, lane = t & 63;
    const int xy = bx * 4 + wv;
    float ls = 0.0f;
    #pragma unroll
    for (int i = 0; i < 4; ++i) {
        int idx = i * 64 + lane;
        int f = idx >> 5;
        float v = fast_elu(coef_m[xy * 8 + f] * cW[idx] + cB[idx]);
        cf_s[wv * 256 + idx] = v;
        ls += __expf(fast_elu(v));
    }
    #pragma unroll
    for (int m = 1; m < 64; m <<= 1) ls += __shfl_xor(ls, m, 64);
    __syncthreads();
    const float rs = __builtin_amdgcn_rcpf(ls);
    const int g = lane & 31, fg = lane >> 5;
    float acc = 0.0f;
    for (int f = fg * 4; f < fg * 4 + 4; ++f) {
        float lin = 0.0f;
        #pragma unroll
        for (int h = 0; h < 32; h += 4) {
            float4 Lv = *reinterpret_cast<const float4*>(&cf_s[wv * 256 + f * 32 + h]);
            float4 Wv = *reinterpret_cast<const float4*>(&attW[f * 1024 + g * 32 + h]);
            lin += Lv.x * Wv.x + Lv.y * Wv.y + Lv.z * Wv.z + Lv.w * Wv.w;
        }
        float e = __expf(fast_elu(cf_s[wv * 256 + f * 32 + g]));
        acc += fast_elu(e * lin * rs);
    }
    part[wv * 64 + lane] = acc;
    __syncthreads();
    if (lane < 32) {
        float tot = part[wv * 64 + lane] + part[wv * 64 + lane + 32];
        cfs[xy * 32 + lane] = fast_elu(tot * 0.125f);
    }
}

static __device__ __forceinline__ void att_phase(
    int o, int ic, float* __restrict__ smemf,
    const float* __restrict__ cfs, const float* __restrict__ oattW,
    float* __restrict__ att)
{
    float* L    = smemf;          // 2048
    float* red  = smemf + 2048;   // 256
    float* csum = smemf + 2304;   // 32
    const int t = threadIdx.x;
    #pragma unroll
    for (int j = 0; j < 8; ++j) L[t + 256 * j] = cfs[o * 2048 + t + 256 * j];
    __syncthreads();
    {
        int h = t & 31, ig = t >> 5;
        float ps = 0.0f;
        for (int i = ig * 8; i < ig * 8 + 8; ++i) ps += __expf(fast_elu(L[i * 32 + h]));
        red[t] = ps;
        __syncthreads();
        if (t < 32) {
            float cs = 0.0f;
            #pragma unroll
            for (int j = 0; j < 8; ++j) cs += red[j * 32 + t];
            csum[t] = cs;
        }
        __syncthreads();
    }
    int idx = ic * 256 + t;
    int i = idx >> 5, g = idx & 31;
    float lin2 = 0.0f;
    #pragma unroll
    for (int h = 0; h < 32; h += 4) {
        float4 Lv = *reinterpret_cast<const float4*>(&L[i * 32 + h]);
        float4 Wv = *reinterpret_cast<const float4*>(&oattW[i * 1024 + g * 32 + h]);
        lin2 += Lv.x * Wv.x + Lv.y * Wv.y + Lv.z * Wv.z + Lv.w * Wv.w;
    }
    float p2 = __expf(fast_elu(L[idx])) * __builtin_amdgcn_rcpf(csum[g]);
    att[o * 2048 + idx] = p2 * lin2;
}

static __device__ __forceinline__ void natt_phase(
    int bx, float* __restrict__ smemf,
    const float* __restrict__ ntW, const float* __restrict__ att,
    unsigned short* __restrict__ nattb)
{
    float* ntW_s = smemf;             // 64*65
    float* att_s = smemf + 64 * 65;   // 64*17
    const int t = threadIdx.x;
    const int d0 = bx * 16;
    #pragma unroll
    for (int j = 0; j < 16; ++j) {
        int idx = t + 256 * j;
        ntW_s[(idx >> 6) * 65 + (idx & 63)] = ntW[idx];
    }
    #pragma unroll
    for (int j = 0; j < 4; ++j) {
        int idx = t + 256 * j;
        int p = idx >> 4, dd = idx & 15;
        att_s[p * 17 + dd] = att[p * 2048 + d0 + dd];
    }
    __syncthreads();
    const int dd = t & 15, ob = (t >> 4) * 4;
    float acc[4] = {0.0f, 0.0f, 0.0f, 0.0f};
    for (int p = 0; p < 64; ++p) {
        float av = att_s[p * 17 + dd];
        #pragma unroll
        for (int i = 0; i < 4; ++i) acc[i] += ntW_s[(ob + i) * 65 + p] * av;
    }
    #pragma unroll
    for (int i = 0; i < 4; ++i)
        nattb[(ob + i) * 2048 + d0 + dd] = f2bf(acc[i]);
}

// generic bf16 GEMM-BT core (mode 0: f32 partial to C+bz*strideCz)
static __device__ __forceinline__ void gemm_core(
    const unsigned short* __restrict__ A, int lda,
    const unsigned short* __restrict__ B, int ldb,
    float* __restrict__ C, int ldc, long strideCz,
    int kchunk, int bn, int bm, int bz,
    unsigned short* __restrict__ As, unsigned short* __restrict__ Bs)
{
    const int t = threadIdx.x;
    const int w = t >> 6, lane = t & 63, l16 = lane & 15, quad = lane >> 4;
    const int n0 = bn * 64, m0 = bm * 64;
    const int kb0 = bz * kchunk;
    const int r = t >> 2, koff = (t & 3) * 8;
    C += (size_t)bz * strideCz;

    const size_t arow = (size_t)(m0 + r) * lda + koff;
    const size_t brow = (size_t)(n0 + r) * ldb + koff;
    bf16x8 av = *reinterpret_cast<const bf16x8*>(&A[arow + kb0]);
    bf16x8 bv = *reinterpret_cast<const bf16x8*>(&B[brow + kb0]);

    f32x4 acc[4] = {};
    for (int kb = kb0; kb < kb0 + kchunk; kb += 32) {
        __syncthreads();
        *reinterpret_cast<bf16x8*>(&As[r * 40 + koff]) = av;
        *reinterpret_cast<bf16x8*>(&Bs[r * 40 + koff]) = bv;
        if (kb + 32 < kb0 + kchunk) {
            av = *reinterpret_cast<const bf16x8*>(&A[arow + kb + 32]);
            bv = *reinterpret_cast<const bf16x8*>(&B[brow + kb + 32]);
        }
        __syncthreads();
        bf16x8 af = *reinterpret_cast<const bf16x8*>(&As[(w * 16 + l16) * 40 + quad * 8]);
        #pragma unroll
        for (int nt = 0; nt < 4; ++nt) {
            bf16x8 bf = *reinterpret_cast<const bf16x8*>(&Bs[(nt * 16 + l16) * 40 + quad * 8]);
            acc[nt] = __builtin_amdgcn_mfma_f32_16x16x32_bf16(af, bf, acc[nt], 0, 0, 0);
        }
    }
    #pragma unroll
    for (int nt = 0; nt < 4; ++nt)
        #pragma unroll
        for (int i = 0; i < 4; ++i) {
            int m = m0 + w * 16 + quad * 4 + i;
            int n = n0 + nt * 16 + l16;
            C[(size_t)m * ldc + n] = acc[nt][i];
        }
}

// fc_in GEMM: A = f32 x [512,2000], B = f32 fc_in_W [1024,2000], cvt fused in
// staging with exact 8-elem masking (2000 = 8*250). Full K, mode-1 epilogue:
// h1b[m*1024+n] = bf16(relu(acc + bias[n])).
static __device__ __forceinline__ void gemm_xf_core(
    const float* __restrict__ A, const float* __restrict__ B,
    const float* __restrict__ bias, unsigned short* __restrict__ Cb,
    int bn, int bm,
    unsigned short* __restrict__ As, unsigned short* __restrict__ Bs)
{
    const int t = threadIdx.x;
    const int w = t >> 6, lane = t & 63, l16 = lane & 15, quad = lane >> 4;
    const int n0 = bn * 64, m0 = bm * 64;
    const int r = t >> 2, koff = (t & 3) * 8;

    const float* arow = A + (size_t)(m0 + r) * 2000;
    const float* brow = B + (size_t)(n0 + r) * 2000;
    const bf16x8 zv = {0, 0, 0, 0, 0, 0, 0, 0};

    bf16x8 av = (koff < 2000) ? cvt8(arow + koff) : zv;
    bf16x8 bv = (koff < 2000) ? cvt8(brow + koff) : zv;

    f32x4 acc[4] = {};
    for (int kb = 0; kb < 2000; kb += 32) {
        __syncthreads();
        *reinterpret_cast<bf16x8*>(&As[r * 40 + koff]) = av;
        *reinterpret_cast<bf16x8*>(&Bs[r * 40 + koff]) = bv;
        if (kb + 32 < 2000) {
            int k = kb + 32 + koff;
            av = (k < 2000) ? cvt8(arow + k) : zv;
            bv = (k < 2000) ? cvt8(brow + k) : zv;
        }
        __syncthreads();
        bf16x8 af = *reinterpret_cast<const bf16x8*>(&As[(w * 16 + l16) * 40 + quad * 8]);
        #pragma unroll
        for (int nt = 0; nt < 4; ++nt) {
            bf16x8 bf = *reinterpret_cast<const bf16x8*>(&Bs[(nt * 16 + l16) * 40 + quad * 8]);
            acc[nt] = __builtin_amdgcn_mfma_f32_16x16x32_bf16(af, bf, acc[nt], 0, 0, 0);
        }
    }
    #pragma unroll
    for (int nt = 0; nt < 4; ++nt)
        #pragma unroll
        for (int i = 0; i < 4; ++i) {
            int m = m0 + w * 16 + quad * 4 + i;
            int n = n0 + nt * 16 + l16;
            float v = acc[nt][i] + bias[n];
            v = fmaxf(v, 0.0f);
            Cb[(size_t)m * 1024 + n] = f2bf(v);
        }
}

// cmat GEMM with A = f32 tgw (cols 64..2112), conversion fused into A-staging
static __device__ __forceinline__ void gemm_tgwa_core(
    const float* __restrict__ tgw,
    const unsigned short* __restrict__ B,   // nattb [64,2048]
    float* __restrict__ C, long strideCz,
    int kchunk, int bm, int bz,
    unsigned short* __restrict__ As, unsigned short* __restrict__ Bs)
{
    const int t = threadIdx.x;
    const int w = t >> 6, lane = t & 63, l16 = lane & 15, quad = lane >> 4;
    const int m0 = bm * 64;
    const int kb0 = bz * kchunk;
    const int r = t >> 2, koff = (t & 3) * 8;
    C += (size_t)bz * strideCz;

    const float* arow = tgw + (size_t)(m0 + r) * 2112 + 64 + koff;
    const unsigned short* brow = B + (size_t)r * 2048 + koff;
    bf16x8 av = cvt8(arow + kb0);
    bf16x8 bv = *reinterpret_cast<const bf16x8*>(brow + kb0);

    f32x4 acc[4] = {};
    for (int kb = kb0; kb < kb0 + kchunk; kb += 32) {
        __syncthreads();
        *reinterpret_cast<bf16x8*>(&As[r * 40 + koff]) = av;
        *reinterpret_cast<bf16x8*>(&Bs[r * 40 + koff]) = bv;
        if (kb + 32 < kb0 + kchunk) {
            av = cvt8(arow + kb + 32);
            bv = *reinterpret_cast<const bf16x8*>(brow + kb + 32);
        }
        __syncthreads();
        bf16x8 af = *reinterpret_cast<const bf16x8*>(&As[(w * 16 + l16) * 40 + quad * 8]);
        #pragma unroll
        for (int nt = 0; nt < 4; ++nt) {
            bf16x8 bf = *reinterpret_cast<const bf16x8*>(&Bs[(nt * 16 + l16) * 40 + quad * 8]);
            acc[nt] = __builtin_amdgcn_mfma_f32_16x16x32_bf16(af, bf, acc[nt], 0, 0, 0);
        }
    }
    #pragma unroll
    for (int nt = 0; nt < 4; ++nt)
        #pragma unroll
        for (int i = 0; i < 4; ++i) {
            int m = m0 + w * 16 + quad * 4 + i;
            int n = nt * 16 + l16;
            C[(size_t)m * 64 + n] = acc[nt][i];
        }
}

// GEMM with A from nparts f32 k-split partials: sum + abias + relu + cvt inline.
// mode 2 epilogue: bf16 relu(acc+bias[perm(n)]) -> Cb
static __device__ __forceinline__ void gemm_fa_core(
    const float* __restrict__ Ap, int lda, long apstride, int nparts,
    const float* __restrict__ abias,
    const unsigned short* __restrict__ B, int ldb,
    unsigned short* __restrict__ Cb, int ldc,
    const float* __restrict__ bias,
    int kchunk, int bn, int bm,
    unsigned short* __restrict__ As, unsigned short* __restrict__ Bs)
{
    const int t = threadIdx.x;
    const int w = t >> 6, lane = t & 63, l16 = lane & 15, quad = lane >> 4;
    const int n0 = bn * 64, m0 = bm * 64;
    const int r = t >> 2, koff = (t & 3) * 8;

    f32x4 acc[4] = {};
    for (int kb = 0; kb < kchunk; kb += 32) {
        float a8[8];
        {
            const float* base = &Ap[(size_t)(m0 + r) * lda + kb + koff];
            float4 s0 = *reinterpret_cast<const float4*>(base);
            float4 s1 = *reinterpret_cast<const float4*>(base + 4);
            for (int j = 1; j < nparts; ++j) {
                const float* pj = base + (size_t)j * apstride;
                float4 p0 = *reinterpret_cast<const float4*>(pj);
                float4 p1 = *reinterpret_cast<const float4*>(pj + 4);
                s0.x += p0.x; s0.y += p0.y; s0.z += p0.z; s0.w += p0.w;
                s1.x += p1.x; s1.y += p1.y; s1.z += p1.z; s1.w += p1.w;
            }
            float4 b0 = *reinterpret_cast<const float4*>(&abias[kb + koff]);
            float4 b1 = *reinterpret_cast<const float4*>(&abias[kb + koff + 4]);
            a8[0] = fmaxf(s0.x + b0.x, 0.0f); a8[1] = fmaxf(s0.y + b0.y, 0.0f);
            a8[2] = fmaxf(s0.z + b0.z, 0.0f); a8[3] = fmaxf(s0.w + b0.w, 0.0f);
            a8[4] = fmaxf(s1.x + b1.x, 0.0f); a8[5] = fmaxf(s1.y + b1.y, 0.0f);
            a8[6] = fmaxf(s1.z + b1.z, 0.0f); a8[7] = fmaxf(s1.w + b1.w, 0.0f);
        }
        bf16x8 bv = *reinterpret_cast<const bf16x8*>(&B[(size_t)(n0 + r) * ldb + kb + koff]);
        __syncthreads();
        ushort4 lo, hi;
        lo.x = f2bf(a8[0]); lo.y = f2bf(a8[1]); lo.z = f2bf(a8[2]); lo.w = f2bf(a8[3]);
        hi.x = f2bf(a8[4]); hi.y = f2bf(a8[5]); hi.z = f2bf(a8[6]); hi.w = f2bf(a8[7]);
        *reinterpret_cast<ushort4*>(&As[r * 40 + koff]) = lo;
        *reinterpret_cast<ushort4*>(&As[r * 40 + koff + 4]) = hi;
        *reinterpret_cast<bf16x8*>(&Bs[r * 40 + koff]) = bv;
        __syncthreads();
        bf16x8 af = *reinterpret_cast<const bf16x8*>(&As[(w * 16 + l16) * 40 + quad * 8]);
        #pragma unroll
        for (int nt = 0; nt < 4; ++nt) {
            bf16x8 bf = *reinterpret_cast<const bf16x8*>(&Bs[(nt * 16 + l16) * 40 + quad * 8]);
            acc[nt] = __builtin_amdgcn_mfma_f32_16x16x32_bf16(af, bf, acc[nt], 0, 0, 0);
        }
    }
    #pragma unroll
    for (int nt = 0; nt < 4; ++nt)
        #pragma unroll
        for (int i = 0; i < 4; ++i) {
            int m = m0 + w * 16 + quad * 4 + i;
            int n = n0 + nt * 16 + l16;
            int bidx = (((n & 63) << 6) | (n >> 6));
            float v = acc[nt][i] + bias[bidx];
            v = fmaxf(v, 0.0f);
            Cb[(size_t)m * ldc + n] = f2bf(v);
        }
}

static __device__ __forceinline__ void nt1f_phase(
    int b, unsigned short* __restrict__ smemu,
    const unsigned short* __restrict__ hbT, const unsigned short* __restrict__ Wb,
    unsigned short* __restrict__ nt1b)
{
    unsigned short* HtT   = smemu;             // [64][72]
    unsigned short* nt1_s = smemu + 64 * 72;   // [64][72]
    const int t = threadIdx.x;
    const int w = t >> 6, lane = t & 63, l16 = lane & 15, quad = lane >> 4;

    const unsigned short* src = hbT + (size_t)b * 4096;
    #pragma unroll
    for (int j = 0; j < 2; ++j) {
        int c = t + j * 256;
        *reinterpret_cast<bf16x8*>(&HtT[(c >> 3) * 72 + (c & 7) * 8]) =
            *reinterpret_cast<const bf16x8*>(&src[c * 8]);
    }
    __syncthreads();

    bf16x8 aW[2];
    #pragma unroll
    for (int h = 0; h < 2; ++h)
        aW[h] = *reinterpret_cast<const bf16x8*>(&Wb[(w * 16 + l16) * 64 + h * 32 + quad * 8]);
    #pragma unroll
    for (int dt = 0; dt < 4; ++dt) {
        f32x4 acc = {0.0f, 0.0f, 0.0f, 0.0f};
        #pragma unroll
        for (int h = 0; h < 2; ++h) {
            bf16x8 bf = *reinterpret_cast<const bf16x8*>(
                &HtT[(dt * 16 + l16) * 72 + h * 32 + quad * 8]);
            acc = __builtin_amdgcn_mfma_f32_16x16x32_bf16(aW[h], bf, acc, 0, 0, 0);
        }
        #pragma unroll
        for (int i = 0; i < 4; ++i)
            nt1_s[(w * 16 + quad * 4 + i) * 72 + dt * 16 + l16] = f2bf(acc[i]);
    }
    __syncthreads();
    #pragma unroll
    for (int j = 0; j < 2; ++j) {
        int c = t + j * 256;
        *reinterpret_cast<bf16x8*>(&nt1b[(size_t)b * 4096 + c * 8]) =
            *reinterpret_cast<const bf16x8*>(&nt1_s[(c >> 3) * 72 + (c & 7) * 8]);
    }
}

// ---------------------------------------------------------------------------
// Uber kernels
// ---------------------------------------------------------------------------
__global__ __launch_bounds__(256) void uber1(   // conv (weights only) + coef
    const float* fc1W, const float* ntW, const float* out1W, const float* tgw,
    unsigned short* fc1Wb, unsigned short* Wb, unsigned short* out1WbT,
    unsigned short* Gb,
    const float* coef_m, const float* cW, const float* cB, const float* attW,
    float* cfs)
{
    __shared__ __align__(16) float smemf[1280];
    int bx = blockIdx.x;
    if (bx < CONV_BLOCKS)
        conv_phase(bx, fc1W, ntW, out1W, tgw, fc1Wb, Wb, out1WbT, Gb);
    else
        coef_phase(bx - CONV_BLOCKS, smemf, coef_m, cW, cB, attW, cfs);
}

__global__ __launch_bounds__(256) void uber2(   // fc_in GEMM (f32-fused, full K) + att
    const float* x, const float* fcinW, const float* fc_in_b,
    unsigned short* h1b,
    const float* cfs, const float* oattW, float* att)
{
    __shared__ __align__(16) float smemf[2592];
    int bx = blockIdx.x;
    if (bx < 128) {
        unsigned short* As = (unsigned short*)smemf;
        gemm_xf_core(x, fcinW, fc_in_b, h1b, bx & 15, bx >> 4, As, As + 2560);
    } else {
        int b2 = bx - 128;
        att_phase(b2 & 63, b2 >> 6, smemf, cfs, oattW, att);
    }
}

__global__ __launch_bounds__(256) void uber3(   // fc1 GEMM (bf16, ksplit 4) + natt
    const unsigned short* h1b, const unsigned short* fc1Wb, float* h2p,
    const float* ntW, const float* att, unsigned short* nattb)
{
    __shared__ __align__(16) float smemf[5248];
    int bx = blockIdx.x;
    if (bx < 64) {
        unsigned short* As = (unsigned short*)smemf;
        gemm_core(h1b, 1024, fc1Wb, 1024, h2p, 128, 65536L,
                  256, bx & 1, (bx >> 1) & 7, bx >> 4, As, As + 2560);
    } else {
        natt_phase(bx - 64, smemf, ntW, att, nattb);
    }
}

__global__ __launch_bounds__(256) void uber4(   // out1 GEMM(fa) + cmat GEMM (ksplit 8)
    const float* h2p, const float* fc1_b, const unsigned short* out1WbT,
    unsigned short* hbT, const float* out1_b,
    const float* tgw, const unsigned short* nattb, float* cpT)
{
    __shared__ __align__(16) float smemf[2560];
    unsigned short* As = (unsigned short*)smemf;
    int bx = blockIdx.x;
    if (bx < 512) {
        gemm_fa_core(h2p, 128, 65536L, 4, fc1_b, out1WbT, 128,
                     hbT, 4096, out1_b, 128, bx & 63, bx >> 6, As, As + 2560);
    } else {
        int b2 = bx - 512;   // [0,264): m in [0,33), z in [0,8)
        gemm_tgwa_core(tgw, nattb, cpT, 135168L, 256,
                       b2 % 33, b2 / 33, As, As + 2560);
    }
}

__global__ __launch_bounds__(256) void uber5(   // nt1f + cmat reduce (nparts=8)
    const unsigned short* hbT, const unsigned short* Wb, unsigned short* nt1b,
    const float* cpT, float* cmatT)
{
    __shared__ __align__(16) unsigned short smemu[2 * 64 * 72];
    int bx = blockIdx.x;
    if (bx < 512) {
        nt1f_phase(bx, smemu, hbT, Wb, nt1b);
    } else {
        int i = (bx - 512) * 256 + threadIdx.x;
        if (i < 135168) {
            float a = 0.0f;
            #pragma unroll
            for (int j = 0; j < 8; ++j) a += cpT[i + (long)j * 135168L];
            cmatT[i] = a;
        }
    }
}

// ---------------------------------------------------------------------------
// final_nb: barrier-free, LDS-free final (verbatim R14). grid (33, 32).
// ---------------------------------------------------------------------------
__global__ __launch_bounds__(256) void final_nb(
    const unsigned short* __restrict__ nt1b, // [512][64][64] bf16
    const unsigned short* __restrict__ Gb,   // [2112,64] bf16
    const float* __restrict__ cmatT,  // [2112,64]
    const float* __restrict__ outW,   // [2112]
    float* __restrict__ zpart)        // [33][512][64]
{
    const int t = threadIdx.x;
    const int w = t >> 6, lane = t & 63, l16 = lane & 15, quad = lane >> 4;
    const int eb = blockIdx.x;
    const int b0 = blockIdx.y * 16;
    const int o = w * 16 + l16;

    bf16x8 ga[4][2];
    float cm[4][4], wv[4][4];
    #pragma unroll
    for (int et = 0; et < 4; ++et) {
        #pragma unroll
        for (int h = 0; h < 2; ++h)
            ga[et][h] = *reinterpret_cast<const bf16x8*>(
                &Gb[(size_t)(eb * 64 + et * 16 + l16) * 64 + h * 32 + quad * 8]);
        #pragma unroll
        for (int i = 0; i < 4; ++i) {
            int e = eb * 64 + et * 16 + quad * 4 + i;
            cm[et][i] = cmatT[(size_t)e * 64 + o];
            wv[et][i] = outW[e];
        }
    }

    const unsigned short* bbase = nt1b + (size_t)b0 * 4096 + o * 64 + quad * 8;
    bf16x8 bf0 = *reinterpret_cast<const bf16x8*>(bbase);
    bf16x8 bf1 = *reinterpret_cast<const bf16x8*>(bbase + 32);

    for (int bi = 0; bi < 16; ++bi) {
        bf16x8 nb0, nb1;
        if (bi < 15) {
            nb0 = *reinterpret_cast<const bf16x8*>(bbase + (size_t)(bi + 1) * 4096);
            nb1 = *reinterpret_cast<const bf16x8*>(bbase + (size_t)(bi + 1) * 4096 + 32);
        }
        float zo = 0.0f;
        #pragma unroll
        for (int et = 0; et < 4; ++et) {
            f32x4 acc = {cm[et][0], cm[et][1], cm[et][2], cm[et][3]};
            acc = __builtin_amdgcn_mfma_f32_16x16x32_bf16(ga[et][0], bf0, acc, 0, 0, 0);
            acc = __builtin_amdgcn_mfma_f32_16x16x32_bf16(ga[et][1], bf1, acc, 0, 0, 0);
            #pragma unroll
            for (int i = 0; i < 4; ++i)
                zo += __builtin_amdgcn_rcpf(1.0f + __expf(-acc[i])) * wv[et][i];
        }
        zo += __shfl_xor(zo, 16, 64);
        zo += __shfl_xor(zo, 32, 64);
        if (quad == 0)
            zpart[((size_t)eb * 512 + b0 + bi) * 64 + o] = zo;
        bf0 = nb0; bf1 = nb1;
    }
}

// out[i] = prelu( sum_z zpart[z][i] + outB )
__global__ __launch_bounds__(256) void finish_kernel(
    const float* __restrict__ zpart, const float* __restrict__ outB,
    const float* __restrict__ preluA, float* __restrict__ out)
{
    int i = blockIdx.x * 256 + threadIdx.x;  // < 32768
    float z = 0.0f;
    for (int j = 0; j < 33; ++j) z += zpart[(size_t)j * 32768 + i];
    z += outB[0];
    float pa = preluA[0];
    out[i] = (z >= 0.0f) ? z : pa * z;
}

extern "C" void kernel_launch(void* const* d_in, const int* in_sizes, int n_in,
                              void* d_out, int out_size, void* d_ws, size_t ws_size,
                              hipStream_t stream)
{
    const float* x       = (const float*)d_in[0];
    const float* fc_in_W = (const float*)d_in[1];
    const float* fc_in_b = (const float*)d_in[2];
    const float* fc1_W   = (const float*)d_in[3];
    const float* fc1_b   = (const float*)d_in[4];
    const float* out1_W  = (const float*)d_in[5];
    const float* out1_b  = (const float*)d_in[6];
    const float* cW      = (const float*)d_in[7];
    const float* cB      = (const float*)d_in[8];
    const float* cattW   = (const float*)d_in[9];
    const float* oattW   = (const float*)d_in[10];
    const float* ntW     = (const float*)d_in[11];
    const float* tgw     = (const float*)d_in[12];
    const float* outW    = (const float*)d_in[13];
    const float* outB    = (const float*)d_in[14];
    const float* preluA  = (const float*)d_in[15];
    const float* coef_m  = (const float*)d_in[16];
    float* out = (float*)d_out;
    float* ws  = (float*)d_ws;

    // workspace layout (float offsets) — no aliasing (~22.6 MB)
    unsigned short* fc1Wb   = (unsigned short*)(ws + 0);          // 65,536 f
    unsigned short* Wb      = (unsigned short*)(ws + 65536);      // 2,048 f
    unsigned short* out1WbT = (unsigned short*)(ws + 67584);      // 262,144 f
    unsigned short* Gb      = (unsigned short*)(ws + 329728);     // 67,584 f
    float*          cfs     = ws + 397312;                        // 131,072 f
    float*          att     = ws + 528384;                        // 131,072 f
    unsigned short* nattb   = (unsigned short*)(ws + 659456);     // 65,536 f
    unsigned short* h1b     = (unsigned short*)(ws + 724992);     // 262,144 f
    float*          h2p     = ws + 987136;                        // 4*65,536 f
    unsigned short* hbT     = (unsigned short*)(ws + 1249280);    // 1,048,576 f
    float*          cpT     = ws + 2297856;                       // 8*135,168 f
    float*          cmatT   = ws + 3379200;                       // 135,168 f
    unsigned short* nt1b    = (unsigned short*)(ws + 3514368);    // 1,048,576 f
    float*          zpart   = ws + 4562944;                       // 1,081,344 f
    // total 5,644,288 floats

    // L1: weight conversions + coef
    uber1<<<CONV_BLOCKS + 1024, 256, 0, stream>>>(
        fc1_W, ntW, out1_W, tgw, fc1Wb, Wb, out1WbT, Gb,
        coef_m, cW, cB, cattW, cfs);
    // L2: fc_in GEMM (f32 inputs, cvt fused, full K, bias+relu epilogue) + att
    uber2<<<640, 256, 0, stream>>>(x, fc_in_W, fc_in_b, h1b, cfs, oattW, att);
    // L3: fc1 GEMM (bf16, ksplit 4) + natt
    uber3<<<192, 256, 0, stream>>>(h1b, fc1Wb, h2p, ntW, att, nattb);
    // L4: out1 GEMM(fa) + cmat GEMM (ksplit 8)
    uber4<<<776, 256, 0, stream>>>(h2p, fc1_b, out1WbT, hbT, out1_b,
                                   tgw, nattb, cpT);
    // L5: nt1f + cmat reduce (nparts=8)
    uber5<<<1040, 256, 0, stream>>>(hbT, Wb, nt1b, cpT, cmatT);
    // L6: barrier-free final, L7: finish
    final_nb<<<dim3(33, 32), 256, 0, stream>>>(nt1b, Gb, cmatT, outW, zpart);
    finish_kernel<<<128, 256, 0, stream>>>(zpart, outB, preluA, out);
}

// Round 16
// 192.785 us; speedup vs baseline: 1.2147x; 1.2147x over previous
//
#include <hip/hip_runtime.h>
#include <math.h>

typedef __attribute__((ext_vector_type(8))) short bf16x8;
typedef __attribute__((ext_vector_type(4))) float f32x4;

static __device__ __forceinline__ float fast_elu(float x) {
    return x > 0.0f ? x : __expf(x) - 1.0f;
}

static __device__ __forceinline__ unsigned short f2bf(float f) {
    unsigned int u = __float_as_uint(f);
    unsigned int r = (u + 0x7FFFu + ((u >> 16) & 1u)) >> 16;
    return (unsigned short)r;
}

static __device__ __forceinline__ bf16x8 cvt8(const float* __restrict__ s) {
    float4 a = *reinterpret_cast<const float4*>(s);
    float4 b = *reinterpret_cast<const float4*>(s + 4);
    bf16x8 r;
    r[0] = (short)f2bf(a.x); r[1] = (short)f2bf(a.y);
    r[2] = (short)f2bf(a.z); r[3] = (short)f2bf(a.w);
    r[4] = (short)f2bf(b.x); r[5] = (short)f2bf(b.y);
    r[6] = (short)f2bf(b.z); r[7] = (short)f2bf(b.w);
    return r;
}

// conv segments in 8-element units (weights only; x/fc_in_W fused into GEMM)
#define T0 16384    // fc1Wb   [128,1024]
#define T1 16896    // Wb      [64,64]
#define T2 82432    // out1WbT [4096,128] row-permuted
#define T3 99328    // Gb      [2112,64] = tgw cols 0:64
#define CONV_BLOCKS 388   // T3/256

// ---------------------------------------------------------------------------
// Phase device functions
// ---------------------------------------------------------------------------
static __device__ __forceinline__ void conv_phase(
    int bx,
    const float* __restrict__ fc1W, const float* __restrict__ ntW,
    const float* __restrict__ out1W, const float* __restrict__ tgw,
    unsigned short* __restrict__ fc1Wb, unsigned short* __restrict__ Wb,
    unsigned short* __restrict__ out1WbT, unsigned short* __restrict__ Gb)
{
    int u = bx * 256 + threadIdx.x;
    if (u < T0) {
        int i8 = u * 8;
        *reinterpret_cast<bf16x8*>(&fc1Wb[i8]) = cvt8(&fc1W[i8]);
    } else if (u < T1) {
        int i8 = (u - T0) * 8;
        *reinterpret_cast<bf16x8*>(&Wb[i8]) = cvt8(&ntW[i8]);
    } else if (u < T2) {
        int i = u - T1;
        int n = i >> 4, kc = i & 15;
        int d = n >> 6, p = n & 63;
        *reinterpret_cast<bf16x8*>(&out1WbT[(size_t)n * 128 + kc * 8]) =
            cvt8(&out1W[(size_t)((p << 6) | d) * 128 + kc * 8]);
    } else if (u < T3) {
        int i = u - T2;
        int e = i >> 3, c = i & 7;
        *reinterpret_cast<bf16x8*>(&Gb[(size_t)e * 64 + c * 8]) =
            cvt8(&tgw[(size_t)e * 2112 + c * 8]);
    }
}

static __device__ __forceinline__ void coef_phase(
    int bx, float* __restrict__ smemf,
    const float* __restrict__ coef_m, const float* __restrict__ cW,
    const float* __restrict__ cB, const float* __restrict__ attW,
    float* __restrict__ cfs)
{
    float* cf_s = smemf;            // [4][256]
    float* part = smemf + 1024;     // [4][64]
    const int t = threadIdx.x;
    const int wv = t >> 6, lane = t & 63;
    const int xy = bx * 4 + wv;
    float ls = 0.0f;
    #pragma unroll
    for (int i = 0; i < 4; ++i) {
        int idx = i * 64 + lane;
        int f = idx >> 5;
        float v = fast_elu(coef_m[xy * 8 + f] * cW[idx] + cB[idx]);
        cf_s[wv * 256 + idx] = v;
        ls += __expf(fast_elu(v));
    }
    #pragma unroll
    for (int m = 1; m < 64; m <<= 1) ls += __shfl_xor(ls, m, 64);
    __syncthreads();
    const float rs = __builtin_amdgcn_rcpf(ls);
    const int g = lane & 31, fg = lane >> 5;
    float acc = 0.0f;
    for (int f = fg * 4; f < fg * 4 + 4; ++f) {
        float lin = 0.0f;
        #pragma unroll
        for (int h = 0; h < 32; h += 4) {
            float4 Lv = *reinterpret_cast<const float4*>(&cf_s[wv * 256 + f * 32 + h]);
            float4 Wv = *reinterpret_cast<const float4*>(&attW[f * 1024 + g * 32 + h]);
            lin += Lv.x * Wv.x + Lv.y * Wv.y + Lv.z * Wv.z + Lv.w * Wv.w;
        }
        float e = __expf(fast_elu(cf_s[wv * 256 + f * 32 + g]));
        acc += fast_elu(e * lin * rs);
    }
    part[wv * 64 + lane] = acc;
    __syncthreads();
    if (lane < 32) {
        float tot = part[wv * 64 + lane] + part[wv * 64 + lane + 32];
        cfs[xy * 32 + lane] = fast_elu(tot * 0.125f);
    }
}

static __device__ __forceinline__ void att_phase(
    int o, int ic, float* __restrict__ smemf,
    const float* __restrict__ cfs, const float* __restrict__ oattW,
    float* __restrict__ att)
{
    float* L    = smemf;          // 2048
    float* red  = smemf + 2048;   // 256
    float* csum = smemf + 2304;   // 32
    const int t = threadIdx.x;
    #pragma unroll
    for (int j = 0; j < 8; ++j) L[t + 256 * j] = cfs[o * 2048 + t + 256 * j];
    __syncthreads();
    {
        int h = t & 31, ig = t >> 5;
        float ps = 0.0f;
        for (int i = ig * 8; i < ig * 8 + 8; ++i) ps += __expf(fast_elu(L[i * 32 + h]));
        red[t] = ps;
        __syncthreads();
        if (t < 32) {
            float cs = 0.0f;
            #pragma unroll
            for (int j = 0; j < 8; ++j) cs += red[j * 32 + t];
            csum[t] = cs;
        }
        __syncthreads();
    }
    int idx = ic * 256 + t;
    int i = idx >> 5, g = idx & 31;
    float lin2 = 0.0f;
    #pragma unroll
    for (int h = 0; h < 32; h += 4) {
        float4 Lv = *reinterpret_cast<const float4*>(&L[i * 32 + h]);
        float4 Wv = *reinterpret_cast<const float4*>(&oattW[i * 1024 + g * 32 + h]);
        lin2 += Lv.x * Wv.x + Lv.y * Wv.y + Lv.z * Wv.z + Lv.w * Wv.w;
    }
    float p2 = __expf(fast_elu(L[idx])) * __builtin_amdgcn_rcpf(csum[g]);
    att[o * 2048 + idx] = p2 * lin2;
}

static __device__ __forceinline__ void natt_phase(
    int bx, float* __restrict__ smemf,
    const float* __restrict__ ntW, const float* __restrict__ att,
    unsigned short* __restrict__ nattb)
{
    float* ntW_s = smemf;             // 64*65
    float* att_s = smemf + 64 * 65;   // 64*17
    const int t = threadIdx.x;
    const int d0 = bx * 16;
    #pragma unroll
    for (int j = 0; j < 16; ++j) {
        int idx = t + 256 * j;
        ntW_s[(idx >> 6) * 65 + (idx & 63)] = ntW[idx];
    }
    #pragma unroll
    for (int j = 0; j < 4; ++j) {
        int idx = t + 256 * j;
        int p = idx >> 4, dd = idx & 15;
        att_s[p * 17 + dd] = att[p * 2048 + d0 + dd];
    }
    __syncthreads();
    const int dd = t & 15, ob = (t >> 4) * 4;
    float acc[4] = {0.0f, 0.0f, 0.0f, 0.0f};
    for (int p = 0; p < 64; ++p) {
        float av = att_s[p * 17 + dd];
        #pragma unroll
        for (int i = 0; i < 4; ++i) acc[i] += ntW_s[(ob + i) * 65 + p] * av;
    }
    #pragma unroll
    for (int i = 0; i < 4; ++i)
        nattb[(ob + i) * 2048 + d0 + dd] = f2bf(acc[i]);
}

// fc_in GEMM with f32 A/B and cvt fused into staging; K padded 2048, ksplit 4
// (kchunk 512, 8-elem mask k<2000). Writes f32 partials C + bz*strideCz.
static __device__ __forceinline__ void gemm_xfs_core(
    const float* __restrict__ A, const float* __restrict__ B,
    float* __restrict__ C, int ldc, long strideCz,
    int bn, int bm, int bz,
    unsigned short* __restrict__ As, unsigned short* __restrict__ Bs)
{
    const int t = threadIdx.x;
    const int w = t >> 6, lane = t & 63, l16 = lane & 15, quad = lane >> 4;
    const int n0 = bn * 64, m0 = bm * 64;
    const int kb0 = bz * 512;
    const int r = t >> 2, koff = (t & 3) * 8;
    C += (size_t)bz * strideCz;

    const float* arow = A + (size_t)(m0 + r) * 2000;
    const float* brow = B + (size_t)(n0 + r) * 2000;
    const bf16x8 zv = {0, 0, 0, 0, 0, 0, 0, 0};
    int k0 = kb0 + koff;
    bf16x8 av = (k0 < 2000) ? cvt8(arow + k0) : zv;
    bf16x8 bv = (k0 < 2000) ? cvt8(brow + k0) : zv;

    f32x4 acc[4] = {};
    for (int kb = kb0; kb < kb0 + 512; kb += 32) {
        __syncthreads();
        *reinterpret_cast<bf16x8*>(&As[r * 40 + koff]) = av;
        *reinterpret_cast<bf16x8*>(&Bs[r * 40 + koff]) = bv;
        if (kb + 32 < kb0 + 512) {
            int k = kb + 32 + koff;
            av = (k < 2000) ? cvt8(arow + k) : zv;
            bv = (k < 2000) ? cvt8(brow + k) : zv;
        }
        __syncthreads();
        bf16x8 af = *reinterpret_cast<const bf16x8*>(&As[(w * 16 + l16) * 40 + quad * 8]);
        #pragma unroll
        for (int nt = 0; nt < 4; ++nt) {
            bf16x8 bf = *reinterpret_cast<const bf16x8*>(&Bs[(nt * 16 + l16) * 40 + quad * 8]);
            acc[nt] = __builtin_amdgcn_mfma_f32_16x16x32_bf16(af, bf, acc[nt], 0, 0, 0);
        }
    }
    #pragma unroll
    for (int nt = 0; nt < 4; ++nt)
        #pragma unroll
        for (int i = 0; i < 4; ++i) {
            int m = m0 + w * 16 + quad * 4 + i;
            int n = n0 + nt * 16 + l16;
            C[(size_t)m * ldc + n] = acc[nt][i];
        }
}

// cmat GEMM with A = f32 tgw (cols 64..2112), conversion fused into A-staging
static __device__ __forceinline__ void gemm_tgwa_core(
    const float* __restrict__ tgw,
    const unsigned short* __restrict__ B,   // nattb [64,2048]
    float* __restrict__ C, long strideCz,
    int kchunk, int bm, int bz,
    unsigned short* __restrict__ As, unsigned short* __restrict__ Bs)
{
    const int t = threadIdx.x;
    const int w = t >> 6, lane = t & 63, l16 = lane & 15, quad = lane >> 4;
    const int m0 = bm * 64;
    const int kb0 = bz * kchunk;
    const int r = t >> 2, koff = (t & 3) * 8;
    C += (size_t)bz * strideCz;

    const float* arow = tgw + (size_t)(m0 + r) * 2112 + 64 + koff;
    const unsigned short* brow = B + (size_t)r * 2048 + koff;
    bf16x8 av = cvt8(arow + kb0);
    bf16x8 bv = *reinterpret_cast<const bf16x8*>(brow + kb0);

    f32x4 acc[4] = {};
    for (int kb = kb0; kb < kb0 + kchunk; kb += 32) {
        __syncthreads();
        *reinterpret_cast<bf16x8*>(&As[r * 40 + koff]) = av;
        *reinterpret_cast<bf16x8*>(&Bs[r * 40 + koff]) = bv;
        if (kb + 32 < kb0 + kchunk) {
            av = cvt8(arow + kb + 32);
            bv = *reinterpret_cast<const bf16x8*>(brow + kb + 32);
        }
        __syncthreads();
        bf16x8 af = *reinterpret_cast<const bf16x8*>(&As[(w * 16 + l16) * 40 + quad * 8]);
        #pragma unroll
        for (int nt = 0; nt < 4; ++nt) {
            bf16x8 bf = *reinterpret_cast<const bf16x8*>(&Bs[(nt * 16 + l16) * 40 + quad * 8]);
            acc[nt] = __builtin_amdgcn_mfma_f32_16x16x32_bf16(af, bf, acc[nt], 0, 0, 0);
        }
    }
    #pragma unroll
    for (int nt = 0; nt < 4; ++nt)
        #pragma unroll
        for (int i = 0; i < 4; ++i) {
            int m = m0 + w * 16 + quad * 4 + i;
            int n = nt * 16 + l16;
            C[(size_t)m * 64 + n] = acc[nt][i];
        }
}

// GEMM with A from nparts f32 k-split partials: sum + abias + relu + cvt inline.
// mode 0: f32 partial -> C + bz*strideCz ; mode 2: bf16 relu(acc+bias[perm]) -> Cb
static __device__ __forceinline__ void gemm_fa_core(
    const float* __restrict__ Ap, int lda, long apstride, int nparts,
    const float* __restrict__ abias,
    const unsigned short* __restrict__ B, int ldb,
    float* __restrict__ C, unsigned short* __restrict__ Cb,
    int ldc, long strideCz, const float* __restrict__ bias,
    int mode, int kchunk, int bn, int bm, int bz,
    unsigned short* __restrict__ As, unsigned short* __restrict__ Bs)
{
    const int t = threadIdx.x;
    const int w = t >> 6, lane = t & 63, l16 = lane & 15, quad = lane >> 4;
    const int n0 = bn * 64, m0 = bm * 64;
    const int kb0 = bz * kchunk;
    const int r = t >> 2, koff = (t & 3) * 8;
    if (mode == 0) C += (size_t)bz * strideCz;

    f32x4 acc[4] = {};
    for (int kb = kb0; kb < kb0 + kchunk; kb += 32) {
        float a8[8];
        {
            const float* base = &Ap[(size_t)(m0 + r) * lda + kb + koff];
            float4 s0 = *reinterpret_cast<const float4*>(base);
            float4 s1 = *reinterpret_cast<const float4*>(base + 4);
            for (int j = 1; j < nparts; ++j) {
                const float* pj = base + (size_t)j * apstride;
                float4 p0 = *reinterpret_cast<const float4*>(pj);
                float4 p1 = *reinterpret_cast<const float4*>(pj + 4);
                s0.x += p0.x; s0.y += p0.y; s0.z += p0.z; s0.w += p0.w;
                s1.x += p1.x; s1.y += p1.y; s1.z += p1.z; s1.w += p1.w;
            }
            float4 b0 = *reinterpret_cast<const float4*>(&abias[kb + koff]);
            float4 b1 = *reinterpret_cast<const float4*>(&abias[kb + koff + 4]);
            a8[0] = fmaxf(s0.x + b0.x, 0.0f); a8[1] = fmaxf(s0.y + b0.y, 0.0f);
            a8[2] = fmaxf(s0.z + b0.z, 0.0f); a8[3] = fmaxf(s0.w + b0.w, 0.0f);
            a8[4] = fmaxf(s1.x + b1.x, 0.0f); a8[5] = fmaxf(s1.y + b1.y, 0.0f);
            a8[6] = fmaxf(s1.z + b1.z, 0.0f); a8[7] = fmaxf(s1.w + b1.w, 0.0f);
        }
        bf16x8 bv = *reinterpret_cast<const bf16x8*>(&B[(size_t)(n0 + r) * ldb + kb + koff]);
        __syncthreads();
        ushort4 lo, hi;
        lo.x = f2bf(a8[0]); lo.y = f2bf(a8[1]); lo.z = f2bf(a8[2]); lo.w = f2bf(a8[3]);
        hi.x = f2bf(a8[4]); hi.y = f2bf(a8[5]); hi.z = f2bf(a8[6]); hi.w = f2bf(a8[7]);
        *reinterpret_cast<ushort4*>(&As[r * 40 + koff]) = lo;
        *reinterpret_cast<ushort4*>(&As[r * 40 + koff + 4]) = hi;
        *reinterpret_cast<bf16x8*>(&Bs[r * 40 + koff]) = bv;
        __syncthreads();
        bf16x8 af = *reinterpret_cast<const bf16x8*>(&As[(w * 16 + l16) * 40 + quad * 8]);
        #pragma unroll
        for (int nt = 0; nt < 4; ++nt) {
            bf16x8 bf = *reinterpret_cast<const bf16x8*>(&Bs[(nt * 16 + l16) * 40 + quad * 8]);
            acc[nt] = __builtin_amdgcn_mfma_f32_16x16x32_bf16(af, bf, acc[nt], 0, 0, 0);
        }
    }
    #pragma unroll
    for (int nt = 0; nt < 4; ++nt)
        #pragma unroll
        for (int i = 0; i < 4; ++i) {
            int m = m0 + w * 16 + quad * 4 + i;
            int n = n0 + nt * 16 + l16;
            if (mode == 0) {
                C[(size_t)m * ldc + n] = acc[nt][i];
            } else {
                int bidx = (((n & 63) << 6) | (n >> 6));
                float v = acc[nt][i] + bias[bidx];
                v = fmaxf(v, 0.0f);
                Cb[(size_t)m * ldc + n] = f2bf(v);
            }
        }
}

static __device__ __forceinline__ void nt1f_phase(
    int b, unsigned short* __restrict__ smemu,
    const unsigned short* __restrict__ hbT, const unsigned short* __restrict__ Wb,
    unsigned short* __restrict__ nt1b)
{
    unsigned short* HtT   = smemu;             // [64][72]
    unsigned short* nt1_s = smemu + 64 * 72;   // [64][72]
    const int t = threadIdx.x;
    const int w = t >> 6, lane = t & 63, l16 = lane & 15, quad = lane >> 4;

    const unsigned short* src = hbT + (size_t)b * 4096;
    #pragma unroll
    for (int j = 0; j < 2; ++j) {
        int c = t + j * 256;
        *reinterpret_cast<bf16x8*>(&HtT[(c >> 3) * 72 + (c & 7) * 8]) =
            *reinterpret_cast<const bf16x8*>(&src[c * 8]);
    }
    __syncthreads();

    bf16x8 aW[2];
    #pragma unroll
    for (int h = 0; h < 2; ++h)
        aW[h] = *reinterpret_cast<const bf16x8*>(&Wb[(w * 16 + l16) * 64 + h * 32 + quad * 8]);
    #pragma unroll
    for (int dt = 0; dt < 4; ++dt) {
        f32x4 acc = {0.0f, 0.0f, 0.0f, 0.0f};
        #pragma unroll
        for (int h = 0; h < 2; ++h) {
            bf16x8 bf = *reinterpret_cast<const bf16x8*>(
                &HtT[(dt * 16 + l16) * 72 + h * 32 + quad * 8]);
            acc = __builtin_amdgcn_mfma_f32_16x16x32_bf16(aW[h], bf, acc, 0, 0, 0);
        }
        #pragma unroll
        for (int i = 0; i < 4; ++i)
            nt1_s[(w * 16 + quad * 4 + i) * 72 + dt * 16 + l16] = f2bf(acc[i]);
    }
    __syncthreads();
    #pragma unroll
    for (int j = 0; j < 2; ++j) {
        int c = t + j * 256;
        *reinterpret_cast<bf16x8*>(&nt1b[(size_t)b * 4096 + c * 8]) =
            *reinterpret_cast<const bf16x8*>(&nt1_s[(c >> 3) * 72 + (c & 7) * 8]);
    }
}

// ---------------------------------------------------------------------------
// Uber kernels
// ---------------------------------------------------------------------------
__global__ __launch_bounds__(256) void uber1(   // weight conversions + coef
    const float* fc1W, const float* ntW, const float* out1W, const float* tgw,
    unsigned short* fc1Wb, unsigned short* Wb, unsigned short* out1WbT,
    unsigned short* Gb,
    const float* coef_m, const float* cW, const float* cB, const float* attW,
    float* cfs)
{
    __shared__ __align__(16) float smemf[1280];
    int bx = blockIdx.x;
    if (bx < CONV_BLOCKS)
        conv_phase(bx, fc1W, ntW, out1W, tgw, fc1Wb, Wb, out1WbT, Gb);
    else
        coef_phase(bx - CONV_BLOCKS, smemf, coef_m, cW, cB, attW, cfs);
}

__global__ __launch_bounds__(256) void uber2(   // fc_in GEMM (f32-fused, ksplit 4) + att
    const float* x, const float* fcinW, float* h1p,
    const float* cfs, const float* oattW, float* att)
{
    __shared__ __align__(16) float smemf[2592];
    int bx = blockIdx.x;
    if (bx < 512) {
        unsigned short* As = (unsigned short*)smemf;
        gemm_xfs_core(x, fcinW, h1p, 1024, 524288L,
                      bx & 15, (bx >> 4) & 7, bx >> 7, As, As + 2560);
    } else {
        int b2 = bx - 512;
        att_phase(b2 & 63, b2 >> 6, smemf, cfs, oattW, att);
    }
}

__global__ __launch_bounds__(256) void uber3(   // fc1 GEMM(fa, nparts=4) + natt
    const float* h1p, const float* fc_in_b, const unsigned short* fc1Wb,
    float* h2p,
    const float* ntW, const float* att, unsigned short* nattb)
{
    __shared__ __align__(16) float smemf[5248];
    int bx = blockIdx.x;
    if (bx < 64) {
        unsigned short* As = (unsigned short*)smemf;
        gemm_fa_core(h1p, 1024, 524288L, 4, fc_in_b, fc1Wb, 1024,
                     h2p, nullptr, 128, 65536L, nullptr, 0, 256,
                     bx & 1, (bx >> 1) & 7, bx >> 4, As, As + 2560);
    } else {
        natt_phase(bx - 64, smemf, ntW, att, nattb);
    }
}

__global__ __launch_bounds__(256) void uber4(   // out1 GEMM(fa) + cmat GEMM (ksplit 8)
    const float* h2p, const float* fc1_b, const unsigned short* out1WbT,
    unsigned short* hbT, const float* out1_b,
    const float* tgw, const unsigned short* nattb, float* cpT)
{
    __shared__ __align__(16) float smemf[2560];
    unsigned short* As = (unsigned short*)smemf;
    int bx = blockIdx.x;
    if (bx < 512) {
        gemm_fa_core(h2p, 128, 65536L, 4, fc1_b, out1WbT, 128,
                     nullptr, hbT, 4096, 0L, out1_b, 2, 128,
                     bx & 63, bx >> 6, 0, As, As + 2560);
    } else {
        int b2 = bx - 512;   // [0,264): m in [0,33), z in [0,8)
        gemm_tgwa_core(tgw, nattb, cpT, 135168L, 256,
                       b2 % 33, b2 / 33, As, As + 2560);
    }
}

__global__ __launch_bounds__(256) void uber5(   // nt1f + cmat reduce (nparts=8)
    const unsigned short* hbT, const unsigned short* Wb, unsigned short* nt1b,
    const float* cpT, float* cmatT)
{
    __shared__ __align__(16) unsigned short smemu[2 * 64 * 72];
    int bx = blockIdx.x;
    if (bx < 512) {
        nt1f_phase(bx, smemu, hbT, Wb, nt1b);
    } else {
        int i = (bx - 512) * 256 + threadIdx.x;
        if (i < 135168) {
            float a = 0.0f;
            #pragma unroll
            for (int j = 0; j < 8; ++j) a += cpT[i + (long)j * 135168L];
            cmatT[i] = a;
        }
    }
}

// ---------------------------------------------------------------------------
// final_nb: barrier-free, LDS-free final (verbatim R14). grid (33, 32).
// ---------------------------------------------------------------------------
__global__ __launch_bounds__(256) void final_nb(
    const unsigned short* __restrict__ nt1b, // [512][64][64] bf16
    const unsigned short* __restrict__ Gb,   // [2112,64] bf16
    const float* __restrict__ cmatT,  // [2112,64]
    const float* __restrict__ outW,   // [2112]
    float* __restrict__ zpart)        // [33][512][64]
{
    const int t = threadIdx.x;
    const int w = t >> 6, lane = t & 63, l16 = lane & 15, quad = lane >> 4;
    const int eb = blockIdx.x;
    const int b0 = blockIdx.y * 16;
    const int o = w * 16 + l16;

    bf16x8 ga[4][2];
    float cm[4][4], wv[4][4];
    #pragma unroll
    for (int et = 0; et < 4; ++et) {
        #pragma unroll
        for (int h = 0; h < 2; ++h)
            ga[et][h] = *reinterpret_cast<const bf16x8*>(
                &Gb[(size_t)(eb * 64 + et * 16 + l16) * 64 + h * 32 + quad * 8]);
        #pragma unroll
        for (int i = 0; i < 4; ++i) {
            int e = eb * 64 + et * 16 + quad * 4 + i;
            cm[et][i] = cmatT[(size_t)e * 64 + o];
            wv[et][i] = outW[e];
        }
    }

    const unsigned short* bbase = nt1b + (size_t)b0 * 4096 + o * 64 + quad * 8;
    bf16x8 bf0 = *reinterpret_cast<const bf16x8*>(bbase);
    bf16x8 bf1 = *reinterpret_cast<const bf16x8*>(bbase + 32);

    for (int bi = 0; bi < 16; ++bi) {
        bf16x8 nb0, nb1;
        if (bi < 15) {
            nb0 = *reinterpret_cast<const bf16x8*>(bbase + (size_t)(bi + 1) * 4096);
            nb1 = *reinterpret_cast<const bf16x8*>(bbase + (size_t)(bi + 1) * 4096 + 32);
        }
        float zo = 0.0f;
        #pragma unroll
        for (int et = 0; et < 4; ++et) {
            f32x4 acc = {cm[et][0], cm[et][1], cm[et][2], cm[et][3]};
            acc = __builtin_amdgcn_mfma_f32_16x16x32_bf16(ga[et][0], bf0, acc, 0, 0, 0);
            acc = __builtin_amdgcn_mfma_f32_16x16x32_bf16(ga[et][1], bf1, acc, 0, 0, 0);
            #pragma unroll
            for (int i = 0; i < 4; ++i)
                zo += __builtin_amdgcn_rcpf(1.0f + __expf(-acc[i])) * wv[et][i];
        }
        zo += __shfl_xor(zo, 16, 64);
        zo += __shfl_xor(zo, 32, 64);
        if (quad == 0)
            zpart[((size_t)eb * 512 + b0 + bi) * 64 + o] = zo;
        bf0 = nb0; bf1 = nb1;
    }
}

// out[i] = prelu( sum_z zpart[z][i] + outB )
__global__ __launch_bounds__(256) void finish_kernel(
    const float* __restrict__ zpart, const float* __restrict__ outB,
    const float* __restrict__ preluA, float* __restrict__ out)
{
    int i = blockIdx.x * 256 + threadIdx.x;  // < 32768
    float z = 0.0f;
    for (int j = 0; j < 33; ++j) z += zpart[(size_t)j * 32768 + i];
    z += outB[0];
    float pa = preluA[0];
    out[i] = (z >= 0.0f) ? z : pa * z;
}

extern "C" void kernel_launch(void* const* d_in, const int* in_sizes, int n_in,
                              void* d_out, int out_size, void* d_ws, size_t ws_size,
                              hipStream_t stream)
{
    const float* x       = (const float*)d_in[0];
    const float* fc_in_W = (const float*)d_in[1];
    const float* fc_in_b = (const float*)d_in[2];
    const float* fc1_W   = (const float*)d_in[3];
    const float* fc1_b   = (const float*)d_in[4];
    const float* out1_W  = (const float*)d_in[5];
    const float* out1_b  = (const float*)d_in[6];
    const float* cW      = (const float*)d_in[7];
    const float* cB      = (const float*)d_in[8];
    const float* cattW   = (const float*)d_in[9];
    const float* oattW   = (const float*)d_in[10];
    const float* ntW     = (const float*)d_in[11];
    const float* tgw     = (const float*)d_in[12];
    const float* outW    = (const float*)d_in[13];
    const float* outB    = (const float*)d_in[14];
    const float* preluA  = (const float*)d_in[15];
    const float* coef_m  = (const float*)d_in[16];
    float* out = (float*)d_out;
    float* ws  = (float*)d_ws;

    // workspace layout (float offsets) — no aliasing (~28.6 MB)
    unsigned short* fc1Wb   = (unsigned short*)(ws + 0);          // 65,536 f
    unsigned short* Wb      = (unsigned short*)(ws + 65536);      // 2,048 f
    unsigned short* out1WbT = (unsigned short*)(ws + 67584);      // 262,144 f
    unsigned short* Gb      = (unsigned short*)(ws + 329728);     // 67,584 f
    float*          cfs     = ws + 397312;                        // 131,072 f
    float*          att     = ws + 528384;                        // 131,072 f
    unsigned short* nattb   = (unsigned short*)(ws + 659456);     // 65,536 f
    float*          h1p     = ws + 724992;                        // 4*524,288 f
    float*          h2p     = ws + 2822144;                       // 4*65,536 f
    unsigned short* hbT     = (unsigned short*)(ws + 3084288);    // 1,048,576 f
    float*          cpT     = ws + 4132864;                       // 8*135,168 f
    float*          cmatT   = ws + 5214208;                       // 135,168 f
    unsigned short* nt1b    = (unsigned short*)(ws + 5349376);    // 1,048,576 f
    float*          zpart   = ws + 6397952;                       // 1,081,344 f
    // total 7,479,296 floats

    // L1: weight conversions + coef
    uber1<<<CONV_BLOCKS + 1024, 256, 0, stream>>>(
        fc1_W, ntW, out1_W, tgw, fc1Wb, Wb, out1WbT, Gb,
        coef_m, cW, cB, cattW, cfs);
    // L2: fc_in GEMM (f32 inputs, cvt fused, ksplit 4) + att
    uber2<<<1024, 256, 0, stream>>>(x, fc_in_W, h1p, cfs, oattW, att);
    // L3: fc1 GEMM(fa, nparts=4) + natt
    uber3<<<192, 256, 0, stream>>>(h1p, fc_in_b, fc1Wb, h2p, ntW, att, nattb);
    // L4: out1 GEMM(fa) + cmat GEMM (ksplit 8)
    uber4<<<776, 256, 0, stream>>>(h2p, fc1_b, out1WbT, hbT, out1_b,
                                   tgw, nattb, cpT);
    // L5: nt1f + cmat reduce (nparts=8)
    uber5<<<1040, 256, 0, stream>>>(hbT, Wb, nt1b, cpT, cmatT);
    // L6: barrier-free final, L7: finish
    final_nb<<<dim3(33, 32), 256, 0, stream>>>(nt1b, Gb, cmatT, outW, zpart);
    finish_kernel<<<128, 256, 0, stream>>>(zpart, outB, preluA, out);
}